// Round 7
// baseline (134.107 us; speedup 1.0000x reference)
//
#include <hip/hip_runtime.h>
#include <hip/hip_fp16.h>
#include <math.h>

#define HIDK 4096
#define NHQ 32
#define HD 128
#define CMAX 4608
#define CLEN 4096
#define NCH 32          // 128-position chunks (2 sequential 64-pos tiles, online softmax)
#define SCALE 0.08838834764831845f   // 1/sqrt(128)

__device__ __forceinline__ float4 ld4(const float* p) { return *reinterpret_cast<const float4*>(p); }
__device__ __forceinline__ float dot4(float4 a, float4 b) { return a.x*b.x + a.y*b.y + a.z*b.z + a.w*b.w; }
// XOR swizzle (dword units, 4-dword granularity): applied on BOTH write and read
__device__ __forceinline__ int kvidx(int pos, int dq) { return pos * 128 + (dq ^ ((pos & 7) << 2)); }

// ---------------------------------------------------------------------------
// GEMM: out[bs,o] = sum_k X[bs,k]*W[o,k]  (M=16, K=4096), 4 waves/block,
// 2 outputs/wave, X double-buffered through LDS. (unchanged)
// ---------------------------------------------------------------------------
__global__ __launch_bounds__(256) void gemm3_kernel(
    const float* __restrict__ X,
    const float* __restrict__ W1, const float* __restrict__ W2, const float* __restrict__ W3,
    int n1, int n2,
    float* __restrict__ o1, int os1,
    float* __restrict__ o2, int os2,
    float* __restrict__ o3, int os3)
{
  __shared__ float Xs[2][16][256];

  const int tid = threadIdx.x, lane = tid & 63, w = tid >> 6;
  const int o = blockIdx.x * 8 + w * 2;

  const float* Wb; float* ob; int os;
  if (o < n1)           { Wb = W1 + (size_t)o * HIDK;            ob = o1 + o;            os = os1; }
  else if (o < n1 + n2) { const int f = o - n1;      Wb = W2 + (size_t)f * HIDK; ob = o2 + f; os = os2; }
  else                  { const int f = o - n1 - n2; Wb = W3 + (size_t)f * HIDK; ob = o3 + f; os = os3; }

  const int strow = tid >> 6;
  const int stcol = (tid & 63) * 4;

  float acc0[16], acc1[16];
  #pragma unroll
  for (int b = 0; b < 16; ++b) { acc0[b] = 0.f; acc1[b] = 0.f; }

  #pragma unroll
  for (int j = 0; j < 4; ++j)
    *(float4*)&Xs[0][strow + j * 4][stcol] = ld4(X + (size_t)(strow + j * 4) * HIDK + stcol);

  int cur = 0;
  #pragma unroll 2
  for (int kt = 0; kt < 16; ++kt) {
    const float4 w0 = ld4(Wb + (size_t)kt * 256 + lane * 4);
    const float4 w1 = ld4(Wb + HIDK + (size_t)kt * 256 + lane * 4);
    float4 g[4];
    if (kt < 15) {
      #pragma unroll
      for (int j = 0; j < 4; ++j)
        g[j] = ld4(X + (size_t)(strow + j * 4) * HIDK + (kt + 1) * 256 + stcol);
    }
    __syncthreads();
    #pragma unroll
    for (int b = 0; b < 16; ++b) {
      const float4 x4 = *(const float4*)&Xs[cur][b][lane * 4];
      acc0[b] += dot4(x4, w0);
      acc1[b] += dot4(x4, w1);
    }
    if (kt < 15) {
      #pragma unroll
      for (int j = 0; j < 4; ++j)
        *(float4*)&Xs[cur ^ 1][strow + j * 4][stcol] = g[j];
    }
    cur ^= 1;
  }

  #pragma unroll
  for (int m = 1; m < 64; m <<= 1)
    #pragma unroll
    for (int b = 0; b < 16; ++b) {
      acc0[b] += __shfl_xor(acc0[b], m, 64);
      acc1[b] += __shfl_xor(acc1[b], m, 64);
    }
  if (lane == 0) {
    #pragma unroll
    for (int b = 0; b < 16; ++b) {
      ob[(size_t)b * os]     = acc0[b];
      ob[(size_t)b * os + 1] = acc1[b];
    }
  }
}

// ---------------------------------------------------------------------------
// Q prep: RoPE * SCALE -> qt[bkv][r][d]  (r = hl*4+s, d = 0..127)
// ---------------------------------------------------------------------------
__global__ __launch_bounds__(256) void qt_prep_kernel(
    const float* __restrict__ qraw, const float* __restrict__ cosp,
    const float* __restrict__ sinp, float* __restrict__ qt)
{
  const int e = blockIdx.x * 256 + threadIdx.x;   // 65536 total
  const int d = e & 127;
  const int r = (e >> 7) & 15;     // hl*4 + s
  const int bkv = e >> 11;         // 0..31
  const int b = bkv >> 3, kv = bkv & 7;
  const int s = r & 3, hl = r >> 2;
  const float* qp = qraw + (size_t)(b * 4 + s) * HIDK + (kv * 4 + hl) * HD;
  const float c  = cosp[(b * 4 + s) * HD + d];
  const float sn = sinp[(b * 4 + s) * HD + d];
  const float sgn = (d < 64) ? -1.f : 1.f;
  qt[e] = (qp[d] * c + sgn * qp[d ^ 64] * sn) * SCALE;
}

// ---------------------------------------------------------------------------
// Attention: 1024 blocks (32 bkv x 32 chunks of 128 pos) x 128 thr (2 waves).
// Wave w owns rows w*8..w*8+7 over the whole chunk. Two sequential 64-pos
// tiles with online softmax. K/V staged COALESCED into one swizzled 32KB LDS
// tile; scores are lane=position (shuffle-free dot); PV coalesced from LDS.
// ---------------------------------------------------------------------------
__global__ __launch_bounds__(128) void attn5_kernel(
    const float* __restrict__ qt, const float* __restrict__ Kc, const float* __restrict__ Vc,
    __half* __restrict__ partOh, float* __restrict__ partM, float* __restrict__ partL)
{
  __shared__ float qsh[16][128];   // 8 KB
  __shared__ float KV[64 * 128];   // 32 KB, swizzled rows, reused K0/V0/K1/V1
  __shared__ float P[64][20];      // 5 KB [pos][row]

  const int tid = threadIdx.x, lane = tid & 63, w = tid >> 6;
  const int chunk = blockIdx.x & 31, bkv = blockIdx.x >> 5;
  const int b = bkv >> 3, kv = bkv & 7;
  const int p0 = chunk * 128;

  const float* Kb = Kc + ((size_t)bkv * CMAX + p0) * HD;
  const float* Vb = Vc + ((size_t)bkv * CMAX + p0) * HD;

  const int dsub = tid & 31;       // staging column (dwords dsub*4)
  const int rp   = tid >> 5;       // staging row phase 0..3

  // stage Q (coalesced) and K tile 0 (coalesced + swizzled)
  #pragma unroll
  for (int j = 0; j < 4; ++j) {
    const int fi = (tid + j * 128) * 4;
    *(float4*)&qsh[0][fi] = ld4(qt + (size_t)bkv * 2048 + fi);
  }
  #pragma unroll
  for (int i = 0; i < 16; ++i) {
    const int pos = i * 4 + rp;
    *(float4*)&KV[kvidx(pos, dsub * 4)] = ld4(Kb + (size_t)pos * HD + dsub * 4);
  }
  __syncthreads();

  float m[8], l[8];
  float4 o[8];
  #pragma unroll
  for (int r = 0; r < 8; ++r) { m[r] = -INFINITY; l[r] = 0.f; o[r] = make_float4(0.f, 0.f, 0.f, 0.f); }

  const int par = lane >> 5, dc = lane & 31;

  #pragma unroll
  for (int t = 0; t < 2; ++t) {
    // ---- scores: lane = position within the 64-pos tile ----
    float sc[8];
    #pragma unroll
    for (int r = 0; r < 8; ++r) sc[r] = 0.f;
    #pragma unroll 8
    for (int d4 = 0; d4 < 32; ++d4) {
      const float4 k4 = *(const float4*)&KV[kvidx(lane, d4 * 4)];
      #pragma unroll
      for (int r = 0; r < 8; ++r)
        sc[r] += dot4(k4, *(const float4*)&qsh[w * 8 + r][d4 * 4]);
    }
    // ---- online softmax (8 rows per wave) ----
    #pragma unroll
    for (int r = 0; r < 8; ++r) {
      float mx = sc[r];
      #pragma unroll
      for (int st = 1; st < 64; st <<= 1) mx = fmaxf(mx, __shfl_xor(mx, st, 64));
      const float mn = fmaxf(m[r], mx);
      const float p  = __expf(sc[r] - mn);
      float ls = p;
      #pragma unroll
      for (int st = 1; st < 64; st <<= 1) ls += __shfl_xor(ls, st, 64);
      const float scal = __expf(m[r] - mn);
      m[r] = mn;
      l[r] = l[r] * scal + ls;
      o[r].x *= scal; o[r].y *= scal; o[r].z *= scal; o[r].w *= scal;
      P[lane][w * 8 + r] = p;
    }
    __syncthreads();               // both waves done reading K tile
    // ---- stage V tile t (overwrites KV) ----
    #pragma unroll
    for (int i = 0; i < 16; ++i) {
      const int pos = i * 4 + rp;
      *(float4*)&KV[kvidx(pos, dsub * 4)] = ld4(Vb + (size_t)(t * 64 + pos) * HD + dsub * 4);
    }
    __syncthreads();
    // ---- PV: lane = (dim-quad dc, pos-parity par) ----
    #pragma unroll 8
    for (int i = 0; i < 32; ++i) {
      const int pos = 2 * i + par;
      const float4 v4 = *(const float4*)&KV[kvidx(pos, dc * 4)];
      const float4 pa = *(const float4*)&P[pos][w * 8];
      const float4 pb = *(const float4*)&P[pos][w * 8 + 4];
      o[0].x += pa.x * v4.x; o[0].y += pa.x * v4.y; o[0].z += pa.x * v4.z; o[0].w += pa.x * v4.w;
      o[1].x += pa.y * v4.x; o[1].y += pa.y * v4.y; o[1].z += pa.y * v4.z; o[1].w += pa.y * v4.w;
      o[2].x += pa.z * v4.x; o[2].y += pa.z * v4.y; o[2].z += pa.z * v4.z; o[2].w += pa.z * v4.w;
      o[3].x += pa.w * v4.x; o[3].y += pa.w * v4.y; o[3].z += pa.w * v4.z; o[3].w += pa.w * v4.w;
      o[4].x += pb.x * v4.x; o[4].y += pb.x * v4.y; o[4].z += pb.x * v4.z; o[4].w += pb.x * v4.w;
      o[5].x += pb.y * v4.x; o[5].y += pb.y * v4.y; o[5].z += pb.y * v4.z; o[5].w += pb.y * v4.w;
      o[6].x += pb.z * v4.x; o[6].y += pb.z * v4.y; o[6].z += pb.z * v4.z; o[6].w += pb.z * v4.w;
      o[7].x += pb.w * v4.x; o[7].y += pb.w * v4.y; o[7].z += pb.w * v4.z; o[7].w += pb.w * v4.w;
    }
    if (t == 0) {
      __syncthreads();             // both waves done reading V tile 0
      #pragma unroll
      for (int i = 0; i < 16; ++i) {
        const int pos = i * 4 + rp;
        *(float4*)&KV[kvidx(pos, dsub * 4)] = ld4(Kb + (size_t)(64 + pos) * HD + dsub * 4);
      }
      __syncthreads();
    }
  }

  // ---- epilogue: combine parities, write fp16 partials ----
  #pragma unroll
  for (int r = 0; r < 8; ++r) {
    o[r].x += __shfl_xor(o[r].x, 32, 64);
    o[r].y += __shfl_xor(o[r].y, 32, 64);
    o[r].z += __shfl_xor(o[r].z, 32, 64);
    o[r].w += __shfl_xor(o[r].w, 32, 64);
  }
  if (lane < 32) {
    #pragma unroll
    for (int r = 0; r < 8; ++r) {
      const int rg = w * 8 + r;
      const int hl = rg >> 2, s = rg & 3;
      const int row = (b * NHQ + kv * 4 + hl) * 4 + s;
      const size_t idx = ((size_t)row * NCH + chunk) * HD + dc * 4;
      *(__half2*)&partOh[idx]     = __floats2half2_rn(o[r].x, o[r].y);
      *(__half2*)&partOh[idx + 2] = __floats2half2_rn(o[r].z, o[r].w);
      if (dc == 0) {
        partM[row * NCH + chunk] = m[r];
        partL[row * NCH + chunk] = l[r];
      }
    }
  }
}

// ---------------------------------------------------------------------------
// Flash-combine 32 chunk partials (fp16) + <=4 new causal tokens. 512 x 64.
// ---------------------------------------------------------------------------
__global__ __launch_bounds__(64) void combine_kernel(
    const float* __restrict__ qt, const float* __restrict__ kraw, const float* __restrict__ vraw,
    const float* __restrict__ cosp, const float* __restrict__ sinp,
    const __half* __restrict__ partOh, const float* __restrict__ partM, const float* __restrict__ partL,
    float* __restrict__ attn)
{
  const int bid = blockIdx.x;             // ((b*32 + h)*4 + s)
  const int s = bid & 3;
  const int h = (bid >> 2) & 31;
  const int b = bid >> 7;
  const int kv = h >> 2;
  const int lane = threadIdx.x;
  const int d0 = lane * 2;

  float M = -INFINITY;
  #pragma unroll 4
  for (int c = 0; c < NCH; ++c) M = fmaxf(M, partM[bid * NCH + c]);

  // roped, scaled q from qt[bkv][r][d]
  const int rloc = (h & 3) * 4 + s;
  const float qr0 = qt[((size_t)(b * 8 + kv) * 16 + rloc) * 128 + d0];
  const float qr1 = qt[((size_t)(b * 8 + kv) * 16 + rloc) * 128 + d0 + 1];

  float sj[4] = {0.f, 0.f, 0.f, 0.f};
  float Mp = M;
  #pragma unroll
  for (int j = 0; j < 4; ++j) {
    if (j <= s) {
      const float* kp = kraw + (size_t)(b * 4 + j) * 1024 + kv * HD;
      const float c0 = cosp[(b * 4 + j) * HD + d0],     sn0 = sinp[(b * 4 + j) * HD + d0];
      const float c1 = cosp[(b * 4 + j) * HD + d0 + 1], sn1 = sinp[(b * 4 + j) * HD + d0 + 1];
      const float sg0 = (d0 < 64) ? -1.f : 1.f;
      const float sg1 = ((d0 + 1) < 64) ? -1.f : 1.f;
      const float kr0 = kp[d0] * c0 + sg0 * kp[d0 ^ 64] * sn0;
      const float kr1 = kp[d0 + 1] * c1 + sg1 * kp[(d0 + 1) ^ 64] * sn1;
      float part = qr0 * kr0 + qr1 * kr1;
      #pragma unroll
      for (int m = 1; m < 64; m <<= 1) part += __shfl_xor(part, m, 64);
      sj[j] = part;
      Mp = fmaxf(Mp, part);
    }
  }

  float ltot = 0.f, O0 = 0.f, O1 = 0.f;
  #pragma unroll 4
  for (int c = 0; c < NCH; ++c) {
    const float a = __expf(partM[bid * NCH + c] - Mp);
    ltot += partL[bid * NCH + c] * a;
    const float2 v = __half22float2(*(const __half2*)&partOh[((size_t)bid * NCH + c) * HD + d0]);
    O0 += a * v.x;
    O1 += a * v.y;
  }
  #pragma unroll
  for (int j = 0; j < 4; ++j) {
    if (j <= s) {
      const float e = __expf(sj[j] - Mp);
      ltot += e;
      const float* vp = vraw + (size_t)(b * 4 + j) * 1024 + kv * HD + d0;
      O0 += e * vp[0];
      O1 += e * vp[1];
    }
  }
  const float inv = 1.f / ltot;
  *(float2*)&attn[(size_t)(b * 4 + s) * HIDK + h * HD + d0] = make_float2(O0 * inv, O1 * inv);
}

// ---------------------------------------------------------------------------
extern "C" void kernel_launch(void* const* d_in, const int* in_sizes, int n_in,
                              void* d_out, int out_size, void* d_ws, size_t ws_size,
                              hipStream_t stream)
{
  const float* hid  = (const float*)d_in[0];
  const float* cosp = (const float*)d_in[1];
  const float* sinp = (const float*)d_in[2];
  const float* Kc   = (const float*)d_in[3];
  const float* Vc   = (const float*)d_in[4];
  const float* Wq   = (const float*)d_in[5];
  const float* Wk   = (const float*)d_in[6];
  const float* Wv   = (const float*)d_in[7];
  const float* Wo   = (const float*)d_in[8];
  float* out = (float*)d_out;

  float* ws    = (float*)d_ws;
  float*  kraw   = ws;                      // 16384
  float*  vraw   = ws + 16384;              // 16384
  float*  attn   = ws + 32768;              // 65536
  float*  qt     = ws + 98304;              // 65536
  float*  qraw   = ws + 163840;             // 65536
  float*  partM  = ws + 229376;             // 512*32 = 16384
  float*  partL  = ws + 245760;             // 16384
  __half* partOh = (__half*)(ws + 262144);  // 512*32*128 halves = 1048576 float-slots
  // total 1,310,720 floats = 5.24 MB

  // A: QKV projection (raw, un-roped)
  gemm3_kernel<<<768, 256, 0, stream>>>(hid, Wq, Wk, Wv, 4096, 1024,
                                        qraw, 4096, kraw, 1024, vraw, 1024);
  // A': RoPE + scale q -> qt[bkv][r][d]
  qt_prep_kernel<<<256, 256, 0, stream>>>(qraw, cosp, sinp, qt);
  // B: attention over the 4096 cached positions
  attn5_kernel<<<1024, 128, 0, stream>>>(qt, Kc, Vc, partOh, partM, partL);
  // C: combine + new causal tokens
  combine_kernel<<<512, 64, 0, stream>>>(qt, kraw, vraw, cosp, sinp,
                                         partOh, partM, partL, attn);
  // D: output projection
  gemm3_kernel<<<512, 256, 0, stream>>>(attn, Wo, Wo, Wo, 4096, 0,
                                        out, 4096, out, 4096, out, 4096);
}